// Round 3
// baseline (771.588 us; speedup 1.0000x reference)
//
#include <hip/hip_runtime.h>

// (B,T,D) = (128, 1024, 64), fp32. out[i][j][t] = prod_{u<=t} (1 + <dX_i(u-1),dY_j(u-1)>/dt)
constexpr int BX    = 128;
constexpr int TT    = 1024;
constexpr int DDIM  = 64;
constexpr int NPAIR = BX * BX;          // 16384
constexpr int LCH   = 8;                // time-chunk length
constexpr int NCH   = TT / LCH;         // 128 chunks
constexpr float DT_INV = 1023.0f;       // 1/dt

// XOR-rotate swizzled LDS index: row stride 64, conflict-free for this access pattern
// (x-reads: 4 addrs/wave, disjoint bank quads; y-reads: 2-way alias = free per m136).
__device__ __forceinline__ int sidx(int row, int col) {
    return (row << 6) + ((col + (row << 2)) & 63);
}

__device__ __forceinline__ float4 f4sub(float4 a, float4 b) {
    return make_float4(a.x - b.x, a.y - b.y, a.z - b.z, a.w - b.w);
}

// Kernel A: 64x64 pair tile x 8-step time chunk. 4x4 micro-tile per thread.
// Register history, float4 (16B) flush every 4 steps -> bounded write amplification.
__global__ __launch_bounds__(256, 2) void zchunk_kernel(const float* __restrict__ X,
                                                        const float* __restrict__ Y,
                                                        float* __restrict__ out,
                                                        float* __restrict__ P)
{
    __shared__ float smX[2][64 * 64];   // 32 KB
    __shared__ float smY[2][64 * 64];   // 32 KB

    const int i0 = blockIdx.x * 64;
    const int j0 = blockIdx.y * 64;
    const int t0 = blockIdx.z * LCH;
    const int tid = (int)threadIdx.x;
    const int ti = tid >> 4;            // 0..15
    const int tj = tid & 15;            // 0..15
    const int col4 = tj << 2;

    const float* xbase[4];
    const float* ybase[4];
#pragma unroll
    for (int k = 0; k < 4; ++k) {
        xbase[k] = X + (size_t)(i0 + ti + 16 * k) * (TT * DDIM) + col4;
        ybase[k] = Y + (size_t)(j0 + ti + 16 * k) * (TT * DDIM) + col4;
    }

    // cx/cy hold X[t0+h]/Y[t0+h] slices; diffs computed against them each step.
    float4 cx[4], cy[4];
    {
        const int sprev = (t0 == 0) ? 0 : t0 - 1;   // t0==0: diff for step 0 is zero
#pragma unroll
        for (int k = 0; k < 4; ++k) {
            const float4 pxk = *(const float4*)(xbase[k] + (size_t)sprev * DDIM);
            const float4 pyk = *(const float4*)(ybase[k] + (size_t)sprev * DDIM);
            cx[k] = *(const float4*)(xbase[k] + (size_t)t0 * DDIM);
            cy[k] = *(const float4*)(ybase[k] + (size_t)t0 * DDIM);
            const int r = ti + 16 * k;
            *(float4*)&smX[0][sidx(r, col4)] = f4sub(cx[k], pxk);
            *(float4*)&smY[0][sidx(r, col4)] = f4sub(cy[k], pyk);
        }
    }

    float cum[4][4];
    float hist[4][4][4];                // [a][b][h&3] — 64 VGPRs, static-indexed
#pragma unroll
    for (int a = 0; a < 4; ++a)
#pragma unroll
        for (int b = 0; b < 4; ++b) cum[a][b] = 1.f;

    __syncthreads();

#pragma unroll
    for (int h = 0; h < LCH; ++h) {
        const int cur = h & 1;

        // prefetch next time slice (latency hidden under the 1024-FMA dot loop)
        float4 nx[4], ny[4];
        if (h + 1 < LCH) {
#pragma unroll
            for (int k = 0; k < 4; ++k) {
                nx[k] = *(const float4*)(xbase[k] + (size_t)(t0 + h + 1) * DDIM);
                ny[k] = *(const float4*)(ybase[k] + (size_t)(t0 + h + 1) * DDIM);
            }
        }

        float d[4][4];
#pragma unroll
        for (int a = 0; a < 4; ++a)
#pragma unroll
            for (int b = 0; b < 4; ++b) d[a][b] = 0.f;

#pragma unroll
        for (int dd = 0; dd < DDIM; dd += 4) {
            float4 xv[4], yv[4];
#pragma unroll
            for (int a = 0; a < 4; ++a) xv[a] = *(const float4*)&smX[cur][sidx(ti + 16 * a, dd)];
#pragma unroll
            for (int b = 0; b < 4; ++b) yv[b] = *(const float4*)&smY[cur][sidx(tj + 16 * b, dd)];
#pragma unroll
            for (int a = 0; a < 4; ++a)
#pragma unroll
                for (int b = 0; b < 4; ++b) {
                    d[a][b] = fmaf(xv[a].x, yv[b].x, d[a][b]);
                    d[a][b] = fmaf(xv[a].y, yv[b].y, d[a][b]);
                    d[a][b] = fmaf(xv[a].z, yv[b].z, d[a][b]);
                    d[a][b] = fmaf(xv[a].w, yv[b].w, d[a][b]);
                }
        }

        // stage next step's diffs into the other buffer; single barrier per step
        if (h + 1 < LCH) {
#pragma unroll
            for (int k = 0; k < 4; ++k) {
                const int r = ti + 16 * k;
                *(float4*)&smX[cur ^ 1][sidx(r, col4)] = f4sub(nx[k], cx[k]);
                *(float4*)&smY[cur ^ 1][sidx(r, col4)] = f4sub(ny[k], cy[k]);
                cx[k] = nx[k];
                cy[k] = ny[k];
            }
            __syncthreads();
        }

        // cumprod update + history; flush 16B per pair every 4 steps
#pragma unroll
        for (int a = 0; a < 4; ++a)
#pragma unroll
            for (int b = 0; b < 4; ++b) {
                cum[a][b] *= fmaf(d[a][b], DT_INV, 1.f);
                hist[a][b][h & 3] = cum[a][b];
            }
        if ((h & 3) == 3) {
            const int tb = t0 + h - 3;
#pragma unroll
            for (int a = 0; a < 4; ++a)
#pragma unroll
                for (int b = 0; b < 4; ++b) {
                    float* o = out + (size_t)((i0 + ti + 16 * a) * BX + (j0 + tj + 16 * b)) * TT + tb;
                    *(float4*)o = make_float4(hist[a][b][0], hist[a][b][1],
                                              hist[a][b][2], hist[a][b][3]);
                }
        }
    }

    // chunk totals, [chunk][pair] layout: adjacent lanes -> adjacent pairs (coalesced)
    const int c = blockIdx.z;
#pragma unroll
    for (int a = 0; a < 4; ++a)
#pragma unroll
        for (int b = 0; b < 4; ++b) {
            const int pair = (i0 + ti + 16 * a) * BX + (j0 + tj + 16 * b);
            P[(size_t)c * NPAIR + pair] = cum[a][b];
        }
}

// Kernel B: in-place exclusive prefix product over chunks per pair.
// [chunk][pair] layout: per-c accesses are coalesced across threads.
__global__ __launch_bounds__(256) void scan_kernel(float* __restrict__ P)
{
    const int p = blockIdx.x * 256 + (int)threadIdx.x;  // 0..16383
    float run = 1.f;
#pragma unroll 4
    for (int c = 0; c < NCH; ++c) {
        const size_t idx = (size_t)c * NPAIR + p;
        const float v = P[idx];
        P[idx] = run;
        run *= v;
    }
}

// Kernel C: out[p][t] *= P[t/LCH][p] — fully coalesced float4 pass.
__global__ __launch_bounds__(256) void scale_kernel(float* __restrict__ out,
                                                    const float* __restrict__ P)
{
    const size_t g    = (size_t)blockIdx.x * 256 + threadIdx.x;
    const size_t base = g * 4;                 // element index, 4 | base
    const int p = (int)(base >> 10);           // /1024
    const int t = (int)(base & (TT - 1));
    const int c = t >> 3;                      // /LCH, uniform across the float4 (4|t)
    const float f = P[(size_t)c * NPAIR + p];
    float4 v = *(float4*)(out + base);
    v.x *= f; v.y *= f; v.z *= f; v.w *= f;
    *(float4*)(out + base) = v;
}

extern "C" void kernel_launch(void* const* d_in, const int* in_sizes, int n_in,
                              void* d_out, int out_size, void* d_ws, size_t ws_size,
                              hipStream_t stream)
{
    const float* X = (const float*)d_in[0];   // (128, 1024, 64) fp32
    const float* Y = (const float*)d_in[1];   // (128, 1024, 64) fp32
    float* out = (float*)d_out;               // (128, 128, 1024) fp32
    float* P   = (float*)d_ws;                // NCH*NPAIR*4 = 8 MB scratch (verified fits)

    zchunk_kernel<<<dim3(2, 2, NCH), 256, 0, stream>>>(X, Y, out, P);
    scan_kernel<<<dim3(NPAIR / 256), 256, 0, stream>>>(P);
    scale_kernel<<<dim3((NPAIR * TT / 4) / 256), 256, 0, stream>>>(out, P);
}

// Round 4
// 213.774 us; speedup vs baseline: 3.6094x; 3.6094x over previous
//
#include <hip/hip_runtime.h>

typedef __attribute__((ext_vector_type(8))) short short8;   // 8 bf16 (4 VGPRs)
typedef __attribute__((ext_vector_type(4))) float floatx4;  // MFMA C/D

// (B,T,D) = (128,1024,64) fp32. out[i][j][t] = prod_{s<=t}(1 + <dX(s-1),dY(s-1)>/dt)
constexpr int BX    = 128;
constexpr int TT    = 1024;
constexpr int DDIM  = 64;
constexpr int NPAIR = BX * BX;
constexpr int LCH   = 16;              // t-steps per block; out flushes are 32B sectors
constexpr int NCH   = TT / LCH;        // 64
constexpr float DT_INV = 1023.0f;

// LDS element index for bf16 rows of 64 with XOR-segment swizzle (16B segments).
// Balanced: every frag read/staging write lands 8 lanes per bank-quad (BW floor).
__device__ __forceinline__ int sidxE(int row, int k) {
    return row * 64 + ((((k >> 3) ^ (row & 7)) << 3) | (k & 7));
}

__device__ __forceinline__ ushort f2bf(float f) {           // round-to-nearest-even bf16
    uint u = __builtin_bit_cast(uint, f);
    u += 0x7fffu + ((u >> 16) & 1u);
    return (ushort)(u >> 16);
}

// 8 floats -> hi/lo bf16 split, two 16B LDS stores.
__device__ __forceinline__ void cvt_store(ushort* hiP, ushort* loP, const float* v) {
    uint hw[4], lw[4];
#pragma unroll
    for (int p = 0; p < 4; ++p) {
        const ushort h0 = f2bf(v[2 * p]), h1 = f2bf(v[2 * p + 1]);
        const float r0 = v[2 * p]     - __builtin_bit_cast(float, (uint)h0 << 16);
        const float r1 = v[2 * p + 1] - __builtin_bit_cast(float, (uint)h1 << 16);
        const ushort l0 = f2bf(r0), l1 = f2bf(r1);
        hw[p] = (uint)h0 | ((uint)h1 << 16);
        lw[p] = (uint)l0 | ((uint)l1 << 16);
    }
    *(uint4*)hiP = make_uint4(hw[0], hw[1], hw[2], hw[3]);
    *(uint4*)loP = make_uint4(lw[0], lw[1], lw[2], lw[3]);
}

__device__ __forceinline__ void ld8(const float* p, float* dst) {
    const float4 a = *(const float4*)p;
    const float4 b = *(const float4*)(p + 4);
    dst[0] = a.x; dst[1] = a.y; dst[2] = a.z; dst[3] = a.w;
    dst[4] = b.x; dst[5] = b.y; dst[6] = b.z; dst[7] = b.w;
}

// Kernel A: 64i x 32j pair tile x 16 t-steps. Split-bf16 3-term MFMA dots.
// grid (2,4,64)=512 blocks (2/CU), 256 thr = 4 waves; wave w: rows w*16..+15, 2 n-subtiles.
__global__ __launch_bounds__(256, 2) void zchunk_kernel(const float* __restrict__ X,
                                                        const float* __restrict__ Y,
                                                        float* __restrict__ out,
                                                        float* __restrict__ P)
{
    __shared__ __align__(16) ushort smXhi[2][64 * 64], smXlo[2][64 * 64];  // 32 KB
    __shared__ __align__(16) ushort smYhi[2][32 * 64], smYlo[2][32 * 64];  // 16 KB

    const int i0 = blockIdx.x * 64;
    const int j0 = blockIdx.y * 32;
    const int t0 = blockIdx.z * LCH;
    const int tid  = (int)threadIdx.x;
    const int lane = tid & 63, w = tid >> 6, quad = lane >> 4, l15 = lane & 15;

    // staging slots: X rows (tid>>3) and (tid>>3)+32; Y row (tid>>3); k-segment tid&7
    const int srow = tid >> 3;          // 0..31
    const int sseg = tid & 7;
    const float* xp0 = X + (size_t)(i0 + srow)      * TT * DDIM + sseg * 8;
    const float* xp1 = X + (size_t)(i0 + srow + 32) * TT * DDIM + sseg * 8;
    const float* yp  = Y + (size_t)(j0 + srow)      * TT * DDIM + sseg * 8;

    float cx0[8], cx1[8], cy[8];        // current slice values (fp32)
    {
        const int sa = (t0 == 0) ? 0 : (t0 - 1);
        float pv[8], d[8];
        ld8(xp0 + (size_t)t0 * DDIM, cx0);
        ld8(xp0 + (size_t)sa * DDIM, pv);
#pragma unroll
        for (int k = 0; k < 8; ++k) d[k] = cx0[k] - pv[k];
        cvt_store(&smXhi[0][sidxE(srow, sseg * 8)], &smXlo[0][sidxE(srow, sseg * 8)], d);

        ld8(xp1 + (size_t)t0 * DDIM, cx1);
        ld8(xp1 + (size_t)sa * DDIM, pv);
#pragma unroll
        for (int k = 0; k < 8; ++k) d[k] = cx1[k] - pv[k];
        cvt_store(&smXhi[0][sidxE(srow + 32, sseg * 8)], &smXlo[0][sidxE(srow + 32, sseg * 8)], d);

        ld8(yp + (size_t)t0 * DDIM, cy);
        ld8(yp + (size_t)sa * DDIM, pv);
#pragma unroll
        for (int k = 0; k < 8; ++k) d[k] = cy[k] - pv[k];
        cvt_store(&smYhi[0][sidxE(srow, sseg * 8)], &smYlo[0][sidxE(srow, sseg * 8)], d);
    }

    float cum[2][4];
    float hist[2][4][8];                // 8-step history -> 32B flushes
#pragma unroll
    for (int s = 0; s < 2; ++s)
#pragma unroll
        for (int r = 0; r < 4; ++r) cum[s][r] = 1.f;

    __syncthreads();

#pragma unroll
    for (int h = 0; h < LCH; ++h) {
        const int cur = h & 1;

        float nx0[8], nx1[8], ny[8];
        if (h + 1 < LCH) {              // prefetch next slice (global latency under MFMA)
            const size_t u = (size_t)(t0 + h + 1) * DDIM;
            ld8(xp0 + u, nx0); ld8(xp1 + u, nx1); ld8(yp + u, ny);
        }

        // A frags for this wave's 16-row strip (row = w*16 + l15, k = kk*32 + quad*8)
        short8 aHi[2], aLo[2];
#pragma unroll
        for (int kk = 0; kk < 2; ++kk) {
            const int e = sidxE(w * 16 + l15, kk * 32 + quad * 8);
            aHi[kk] = *(const short8*)&smXhi[cur][e];
            aLo[kk] = *(const short8*)&smXlo[cur][e];
        }

#pragma unroll
        for (int sub = 0; sub < 2; ++sub) {
            floatx4 acc = {0.f, 0.f, 0.f, 0.f};
#pragma unroll
            for (int kk = 0; kk < 2; ++kk) {
                const int e = sidxE(sub * 16 + l15, kk * 32 + quad * 8);
                const short8 bHi = *(const short8*)&smYhi[cur][e];
                const short8 bLo = *(const short8*)&smYlo[cur][e];
                acc = __builtin_amdgcn_mfma_f32_16x16x32_bf16(aLo[kk], bHi, acc, 0, 0, 0);
                acc = __builtin_amdgcn_mfma_f32_16x16x32_bf16(aHi[kk], bLo, acc, 0, 0, 0);
                acc = __builtin_amdgcn_mfma_f32_16x16x32_bf16(aHi[kk], bHi, acc, 0, 0, 0);
            }
#pragma unroll
            for (int r = 0; r < 4; ++r) {
                cum[sub][r] *= fmaf(acc[r], DT_INV, 1.f);
                hist[sub][r][h & 7] = cum[sub][r];
            }
        }

        if (h + 1 < LCH) {              // stage next step's diffs into other buffer
            float d[8];
#pragma unroll
            for (int k = 0; k < 8; ++k) d[k] = nx0[k] - cx0[k];
            cvt_store(&smXhi[cur ^ 1][sidxE(srow, sseg * 8)], &smXlo[cur ^ 1][sidxE(srow, sseg * 8)], d);
#pragma unroll
            for (int k = 0; k < 8; ++k) d[k] = nx1[k] - cx1[k];
            cvt_store(&smXhi[cur ^ 1][sidxE(srow + 32, sseg * 8)], &smXlo[cur ^ 1][sidxE(srow + 32, sseg * 8)], d);
#pragma unroll
            for (int k = 0; k < 8; ++k) d[k] = ny[k] - cy[k];
            cvt_store(&smYhi[cur ^ 1][sidxE(srow, sseg * 8)], &smYlo[cur ^ 1][sidxE(srow, sseg * 8)], d);
#pragma unroll
            for (int k = 0; k < 8; ++k) { cx0[k] = nx0[k]; cx1[k] = nx1[k]; cy[k] = ny[k]; }
            __syncthreads();
        }

        if ((h & 7) == 7) {             // 32B-aligned full-sector flush (NO sub-sector stores!)
            const int tb = t0 + h - 7;
#pragma unroll
            for (int sub = 0; sub < 2; ++sub)
#pragma unroll
                for (int r = 0; r < 4; ++r) {
                    float* o = out + (size_t)((i0 + w * 16 + quad * 4 + r) * BX +
                                              (j0 + sub * 16 + l15)) * TT + tb;
                    *(float4*)o       = make_float4(hist[sub][r][0], hist[sub][r][1],
                                                    hist[sub][r][2], hist[sub][r][3]);
                    *(float4*)(o + 4) = make_float4(hist[sub][r][4], hist[sub][r][5],
                                                    hist[sub][r][6], hist[sub][r][7]);
                }
        }
    }

    // chunk totals, [chunk][pair] (coalesced-ish scatter, 4 MB total)
#pragma unroll
    for (int sub = 0; sub < 2; ++sub)
#pragma unroll
        for (int r = 0; r < 4; ++r) {
            const int pair = (i0 + w * 16 + quad * 4 + r) * BX + (j0 + sub * 16 + l15);
            P[(size_t)blockIdx.z * NPAIR + pair] = cum[sub][r];
        }
}

// Kernel B: exclusive prefix product over chunks per pair ([chunk][pair], coalesced).
__global__ __launch_bounds__(256) void scan_kernel(float* __restrict__ P)
{
    const int p = blockIdx.x * 256 + (int)threadIdx.x;
    float run = 1.f;
#pragma unroll 4
    for (int c = 0; c < NCH; ++c) {
        const size_t idx = (size_t)c * NPAIR + p;
        const float v = P[idx];
        P[idx] = run;
        run *= v;
    }
}

// Kernel C: out[p][t] *= P[t/LCH][p] — coalesced float4 pass.
__global__ __launch_bounds__(256) void scale_kernel(float* __restrict__ out,
                                                    const float* __restrict__ P)
{
    const size_t g    = (size_t)blockIdx.x * 256 + threadIdx.x;
    const size_t base = g * 4;
    const int p = (int)(base >> 10);
    const int t = (int)(base & (TT - 1));
    const float f = P[(size_t)(t >> 4) * NPAIR + p];
    float4 v = *(float4*)(out + base);
    v.x *= f; v.y *= f; v.z *= f; v.w *= f;
    *(float4*)(out + base) = v;
}

extern "C" void kernel_launch(void* const* d_in, const int* in_sizes, int n_in,
                              void* d_out, int out_size, void* d_ws, size_t ws_size,
                              hipStream_t stream)
{
    const float* X = (const float*)d_in[0];
    const float* Y = (const float*)d_in[1];
    float* out = (float*)d_out;
    float* P   = (float*)d_ws;          // NCH*NPAIR*4 = 4 MB

    zchunk_kernel<<<dim3(2, 4, NCH), 256, 0, stream>>>(X, Y, out, P);
    scan_kernel<<<dim3(NPAIR / 256), 256, 0, stream>>>(P);
    scale_kernel<<<dim3((NPAIR * TT / 4) / 256), 256, 0, stream>>>(out, P);
}